// Round 1
// baseline (1733.077 us; speedup 1.0000x reference)
//
#include <hip/hip_runtime.h>
#include <math.h>

// Problem: B=8, L=512, D=512, H=8, Dh=64
// inputs [B,L,D] f32; Wq/Wk/Wv [D, H*Dh]; Wp [D, 3H]; bp [3H];
// prev_state/prev_momentum [B,H,Dh,Dh]
// outputs: readout [B,L,H*Dh], state_seq [B,L,H,Dh,Dh], mom_seq [B,L,H,Dh,Dh]

#define Bb 8
#define Ll 512
#define Dd 512
#define Hh 8
#define Dh 64
#define Mrows (Bb*Ll)          // 4096

// ---------------- fp32 tiled GEMM: C[M,N] = A[M,K] * B[K,N] ----------------
// BM=64 BN=64 BK=16, 256 threads, 4x4 microtile per thread.
__global__ __launch_bounds__(256) void gemm_f32(const float* __restrict__ A,
                                                const float* __restrict__ Bm,
                                                float* __restrict__ C,
                                                int M, int N, int K) {
    __shared__ float As[16][64];   // [k][m] (A transposed in LDS)
    __shared__ float Bs[16][64];   // [k][n]
    const int tid = threadIdx.x;
    const int bm = blockIdx.y * 64;
    const int bn = blockIdx.x * 64;
    const int tx = tid & 15;       // n-tile 0..15
    const int ty = tid >> 4;       // m-tile 0..15
    const int ty4 = ty * 4, tx4 = tx * 4;

    // A staging: thread loads float4 at row ra=tid/4, cols ka..ka+3
    const int ra = tid >> 2;
    const int ka = (tid & 3) << 2;
    // B staging: thread loads float4 at row kb=tid/16, cols nb..nb+3
    const int kb = tid >> 4;
    const int nb = (tid & 15) << 2;

    const float* Aptr = A + (size_t)(bm + ra) * K + ka;
    const float* Bptr = Bm + (size_t)kb * N + bn + nb;

    float acc[4][4];
#pragma unroll
    for (int i = 0; i < 4; ++i)
#pragma unroll
        for (int j = 0; j < 4; ++j) acc[i][j] = 0.f;

    for (int k0 = 0; k0 < K; k0 += 16) {
        float4 av = *(const float4*)(Aptr + k0);
        float4 bv = *(const float4*)(Bptr + (size_t)k0 * N);
        __syncthreads();
        As[ka + 0][ra] = av.x;
        As[ka + 1][ra] = av.y;
        As[ka + 2][ra] = av.z;
        As[ka + 3][ra] = av.w;
        *(float4*)&Bs[kb][nb] = bv;
        __syncthreads();
#pragma unroll
        for (int kk = 0; kk < 16; ++kk) {
            float a[4], b[4];
            *(float4*)a = *(const float4*)&As[kk][ty4];
            *(float4*)b = *(const float4*)&Bs[kk][tx4];
#pragma unroll
            for (int i = 0; i < 4; ++i)
#pragma unroll
                for (int j = 0; j < 4; ++j)
                    acc[i][j] = fmaf(a[i], b[j], acc[i][j]);
        }
    }
#pragma unroll
    for (int i = 0; i < 4; ++i) {
        float4 o = make_float4(acc[i][0], acc[i][1], acc[i][2], acc[i][3]);
        *(float4*)&C[(size_t)(bm + ty4 + i) * N + bn + tx4] = o;
    }
}

// ---------------- p projection: P[M,24] = X[M,512]*Wp[512,24] + bp ----------
__global__ __launch_bounds__(256) void pproj(const float* __restrict__ X,
                                             const float* __restrict__ Wp,
                                             const float* __restrict__ bp,
                                             float* __restrict__ P) {
    __shared__ float W[Dd * 24];   // 48 KB
    const int tid = threadIdx.x;
    for (int i = tid; i < Dd * 24; i += 256) W[i] = Wp[i];
    __syncthreads();
    const int row0 = blockIdx.x * 64;
    for (int o = tid; o < 64 * 24; o += 256) {
        const int r = o / 24, c = o % 24;
        const float* x = X + (size_t)(row0 + r) * Dd;
        float acc = bp[c];
        for (int k = 0; k < Dd; ++k) acc = fmaf(x[k], W[k * 24 + c], acc);
        P[(size_t)(row0 + r) * 24 + c] = acc;
    }
}

__device__ __forceinline__ float wave_sum64(float v) {
#pragma unroll
    for (int m = 1; m < 64; m <<= 1) v += __shfl_xor(v, m, 64);
    return v;
}

// ---------------- k row L2-normalize (wave per row of 64) -------------------
__global__ __launch_bounds__(256) void knorm(float* __restrict__ Km, int rows) {
    const int r = blockIdx.x * 4 + (threadIdx.x >> 6);
    const int j = threadIdx.x & 63;
    if (r >= rows) return;
    float v = Km[(size_t)r * 64 + j];
    float ss = wave_sum64(v * v);
    float nrm = fmaxf(sqrtf(ss), 1e-12f);
    Km[(size_t)r * 64 + j] = v / nrm;
}

// ---------------- the scan: one wave per (b,h,i) row ------------------------
// state row s_j, mom row m_j live in registers (one float each per lane).
__global__ __launch_bounds__(256) void titan_scan(const float* __restrict__ Q,
                                                  const float* __restrict__ K,
                                                  const float* __restrict__ V,
                                                  const float* __restrict__ P,
                                                  const float* __restrict__ prev_state,
                                                  const float* __restrict__ prev_mom,
                                                  float* __restrict__ readout,
                                                  float* __restrict__ state_seq,
                                                  float* __restrict__ mom_seq) {
    const int r = blockIdx.x * 4 + (threadIdx.x >> 6);   // 0..4095
    const int j = threadIdx.x & 63;
    const int b = r >> 9;          // /(H*Dh)
    const int h = (r >> 6) & 7;
    const int i = r & 63;

    const size_t init_off = ((size_t)(b * Hh + h) * Dh + i) * Dh + j;
    float s = prev_state[init_off];
    float m = prev_mom[init_off];

    for (int t = 0; t < Ll; ++t) {
        const size_t base = ((size_t)(b * Ll + t) * Hh + h) * Dh;
        const float kj = K[base + j];
        const float qj = Q[base + j];
        const float vi = V[base + i];
        const size_t pb = (size_t)(b * Ll + t) * 24 + h;
        const float p0 = P[pb];          // alpha logit
        const float p1 = P[pb + 8];      // eta logit
        const float p2 = P[pb + 16];     // theta pre-softplus
        const float alpha = 1.f / (1.f + __expf(-p0));
        const float eta = 1.f / (1.f + __expf(-p1));
        // stable softplus
        const float theta = fmaxf(p2, 0.f) + log1pf(__expf(-fabsf(p2)));

        const float vh = wave_sum64(s * kj);
        const float y = wave_sum64(s * qj);

        const float grad = (vh - vi) * kj;
        m = eta * m - theta * grad;
        s = (1.f - alpha) * s + m;

        const size_t ob = base * Dh + (size_t)i * Dh + j;  // [B,L,H,Dh,Dh]
        state_seq[ob] = s;
        mom_seq[ob] = m;
        if (j == 0) readout[base + i] = y;
    }
}

extern "C" void kernel_launch(void* const* d_in, const int* in_sizes, int n_in,
                              void* d_out, int out_size, void* d_ws, size_t ws_size,
                              hipStream_t stream) {
    const float* inputs = (const float*)d_in[0];
    const float* Wq = (const float*)d_in[1];
    const float* Wk = (const float*)d_in[2];
    const float* Wv = (const float*)d_in[3];
    const float* Wp = (const float*)d_in[4];
    const float* bp = (const float*)d_in[5];
    const float* prev_state = (const float*)d_in[6];
    const float* prev_mom = (const float*)d_in[7];

    float* out = (float*)d_out;
    float* readout = out;                                   // 8*512*512
    float* state_seq = out + (size_t)Bb * Ll * Hh * Dh;     // + 2,097,152
    float* mom_seq = state_seq + (size_t)Bb * Ll * Hh * Dh * Dh;

    float* ws = (float*)d_ws;
    float* q = ws;                                  // 4096*512
    float* k = q + (size_t)Mrows * Dd;
    float* v = k + (size_t)Mrows * Dd;
    float* p = v + (size_t)Mrows * Dd;              // 4096*24

    dim3 gGrid(Dd / 64, Mrows / 64);                // (8, 64)
    gemm_f32<<<gGrid, 256, 0, stream>>>(inputs, Wq, q, Mrows, Dd, Dd);
    gemm_f32<<<gGrid, 256, 0, stream>>>(inputs, Wk, k, Mrows, Dd, Dd);
    gemm_f32<<<gGrid, 256, 0, stream>>>(inputs, Wv, v, Mrows, Dd, Dd);
    pproj<<<Mrows / 64, 256, 0, stream>>>(inputs, Wp, bp, p);
    knorm<<<(Mrows * Hh) / 4, 256, 0, stream>>>(k, Mrows * Hh);
    titan_scan<<<(Bb * Hh * Dh) / 4, 256, 0, stream>>>(q, k, v, p, prev_state,
                                                       prev_mom, readout,
                                                       state_seq, mom_seq);
}